// Round 1
// baseline (555.943 us; speedup 1.0000x reference)
//
#include <hip/hip_runtime.h>

#define TT 512
#define BB 512
#define NN 64

__device__ __forceinline__ float wave_max(float v) {
    #pragma unroll
    for (int off = 32; off > 0; off >>= 1)
        v = fmaxf(v, __shfl_xor(v, off, 64));
    return v;
}

__device__ __forceinline__ float wave_sum(float v) {
    #pragma unroll
    for (int off = 32; off > 0; off >>= 1)
        v += __shfl_xor(v, off, 64);
    return v;
}

// Zero the scalar output (harness poisons d_out with 0xAA before every launch).
__global__ void zero_kernel(float* __restrict__ out) {
    if (threadIdx.x == 0 && blockIdx.x == 0) out[0] = 0.0f;
}

// Forward algorithm: one wave (64 lanes) per batch element; lane = state k.
// alpha_new[k] = emit[t,b,k] + m + log( sum_j exp(alpha_j - m) * exp(trans[j,k]) )
// E = exp(trans) precomputed into 64 registers per lane.
__global__ __launch_bounds__(64) void crf_fwd_kernel(
    const float* __restrict__ emit,
    const float* __restrict__ trans,
    const float* __restrict__ strans,
    const float* __restrict__ etrans,
    const void*  __restrict__ maskp,
    float* __restrict__ out)
{
    const int b = blockIdx.x;
    const int k = threadIdx.x;

    __shared__ __align__(16) float pbuf[NN];

    const int*           mi32 = (const int*)maskp;
    const unsigned char* mi8  = (const unsigned char*)maskp;
    // mask[0,:] is all-true (lengths >= 1): int32 encoding -> word0 == 1,
    // byte encoding -> word0 == 0x01010101.
    const bool bytemode = (mi32[0] == 0x01010101);

    // E[j] = exp(trans[j][k]); trans is ~N(0, 1/64)*... |trans| small, safe.
    float E[NN];
    #pragma unroll
    for (int j = 0; j < NN; ++j)
        E[j] = __expf(trans[j * NN + k]);

    // t = 0: alpha = emit[0,b,k] + strans[k]
    float alpha = emit[(size_t)b * NN + k] + strans[k];

    for (int t = 1; t < TT; ++t) {
        const size_t tb = (size_t)t * BB + b;
        const int mk = bytemode ? (int)mi8[tb] : mi32[tb];
        if (!mk) break;  // mask is monotone per batch: t < len[b]

        // independent global load, issued early to overlap with reduction
        const float emit_t = emit[tb * NN + k];

        const float m = wave_max(alpha);
        const float p = __expf(alpha - m);

        __syncthreads();           // previous iteration's pbuf reads complete
        pbuf[k] = p;
        __syncthreads();           // writes visible

        const float4* p4 = (const float4*)pbuf;
        float a0 = 0.f, a1 = 0.f, a2 = 0.f, a3 = 0.f;
        #pragma unroll
        for (int jj = 0; jj < NN / 4; ++jj) {
            const float4 pv = p4[jj];   // same-address broadcast read (conflict-free)
            a0 = fmaf(pv.x, E[4 * jj + 0], a0);
            a1 = fmaf(pv.y, E[4 * jj + 1], a1);
            a2 = fmaf(pv.z, E[4 * jj + 2], a2);
            a3 = fmaf(pv.w, E[4 * jj + 3], a3);
        }
        const float acc = (a0 + a1) + (a2 + a3);

        alpha = m + __logf(acc) + emit_t;
    }

    // logZ_b = logsumexp_k(alpha + etrans)
    const float la = alpha + etrans[k];
    const float m2 = wave_max(la);
    const float s2 = wave_sum(__expf(la - m2));
    if (k == 0) atomicAdd(out, m2 + __logf(s2));
}

// Gold score: sum over masked (t,b) of emit[t,b,tgt] (+ trans[tgt_prev,tgt] for t>0,
// + strans[tgt] for t==0, + etrans[tgt] at the last masked step). Subtracted from out.
__global__ __launch_bounds__(256) void crf_gold_kernel(
    const float* __restrict__ emit,
    const float* __restrict__ trans,
    const float* __restrict__ strans,
    const float* __restrict__ etrans,
    const int*   __restrict__ target,
    const void*  __restrict__ maskp,
    float* __restrict__ out)
{
    const int*           mi32 = (const int*)maskp;
    const unsigned char* mi8  = (const unsigned char*)maskp;
    const bool bytemode = (mi32[0] == 0x01010101);

    const int stride = gridDim.x * blockDim.x;
    float acc = 0.f;
    for (int i = blockIdx.x * blockDim.x + threadIdx.x; i < TT * BB; i += stride) {
        const int t = i >> 9;        // i / 512
        const bool mk = bytemode ? (mi8[i] != 0) : (mi32[i] != 0);
        if (mk) {
            const int tgt = target[i];
            float v = emit[(size_t)i * NN + tgt];
            if (t > 0)
                v += trans[target[i - BB] * NN + tgt];
            else
                v += strans[tgt];
            const bool is_end = (t == TT - 1) ||
                (bytemode ? (mi8[i + BB] == 0) : (mi32[i + BB] == 0));
            if (is_end) v += etrans[tgt];
            acc += v;
        }
    }

    // block reduction: wave shfl-reduce, then LDS across the 4 waves
    acc = wave_sum(acc);
    __shared__ float wsum[4];
    const int wid = threadIdx.x >> 6;
    if ((threadIdx.x & 63) == 0) wsum[wid] = acc;
    __syncthreads();
    if (threadIdx.x == 0) {
        const float s = (wsum[0] + wsum[1]) + (wsum[2] + wsum[3]);
        atomicAdd(out, -s);
    }
}

extern "C" void kernel_launch(void* const* d_in, const int* in_sizes, int n_in,
                              void* d_out, int out_size, void* d_ws, size_t ws_size,
                              hipStream_t stream) {
    const float* emit   = (const float*)d_in[0];
    const float* trans  = (const float*)d_in[1];
    const float* strans = (const float*)d_in[2];
    const float* etrans = (const float*)d_in[3];
    const int*   target = (const int*)d_in[4];
    const void*  mask   = d_in[5];
    float* out = (float*)d_out;

    hipLaunchKernelGGL(zero_kernel, dim3(1), dim3(64), 0, stream, out);
    hipLaunchKernelGGL(crf_fwd_kernel, dim3(BB), dim3(64), 0, stream,
                       emit, trans, strans, etrans, mask, out);
    hipLaunchKernelGGL(crf_gold_kernel, dim3(256), dim3(256), 0, stream,
                       emit, trans, strans, etrans, target, mask, out);
}

// Round 2
// 327.710 us; speedup vs baseline: 1.6964x; 1.6964x over previous
//
#include <hip/hip_runtime.h>

#define TT 512
#define BB 512
#define NN 64

__device__ __forceinline__ float wave_max(float v) {
    #pragma unroll
    for (int off = 32; off > 0; off >>= 1)
        v = fmaxf(v, __shfl_xor(v, off, 64));
    return v;
}

__device__ __forceinline__ float wave_sum(float v) {
    #pragma unroll
    for (int off = 32; off > 0; off >>= 1)
        v += __shfl_xor(v, off, 64);
    return v;
}

__device__ __forceinline__ int wave_sum_i(int v) {
    #pragma unroll
    for (int off = 32; off > 0; off >>= 1)
        v += __shfl_xor(v, off, 64);
    return v;
}

// Zero the scalar output (harness poisons d_out with 0xAA before every launch).
__global__ void zero_kernel(float* __restrict__ out) {
    if (threadIdx.x == 0 && blockIdx.x == 0) out[0] = 0.0f;
}

// Forward algorithm: one wave (64 lanes) per batch element; lane = state k.
// alpha_new[k] = emit[t,b,k] + a0 + log( sum_j exp(alpha_j - a0) * exp(trans[j,k]) )
// a0 = readfirstlane(alpha) (cheap shift; exact max not needed — spread <= ~8 nats).
__global__ __launch_bounds__(64) void crf_fwd_kernel(
    const float* __restrict__ emit,
    const float* __restrict__ trans,
    const float* __restrict__ strans,
    const float* __restrict__ etrans,
    const void*  __restrict__ maskp,
    float* __restrict__ out)
{
    const int b = blockIdx.x;
    const int k = threadIdx.x;

    __shared__ __align__(16) float pbuf[NN];

    const int*           mi32 = (const int*)maskp;
    const unsigned char* mi8  = (const unsigned char*)maskp;
    // mask[0,:] is all-true (lengths >= 1): byte encoding -> word0 == 0x01010101.
    const bool bytemode = (mi32[0] == 0x01010101);

    // len[b] = sum_t mask[t,b]  (mask is monotone per column). One-time cost;
    // removes the per-step dependent mask load from the T-loop critical path.
    int cnt = 0;
    #pragma unroll
    for (int i = 0; i < TT / 64; ++i) {
        const size_t tb = (size_t)(i * 64 + k) * BB + b;
        cnt += bytemode ? (mi8[tb] != 0) : (mi32[tb] != 0);
    }
    const int len = wave_sum_i(cnt);   // wave-uniform

    // E[j] = exp(trans[j][k]); |trans| ~< 0.6, E in [~0.6, ~1.7].
    float E[NN];
    #pragma unroll
    for (int j = 0; j < NN; ++j)
        E[j] = __expf(trans[j * NN + k]);

    // t = 0
    float alpha = emit[(size_t)b * NN + k] + strans[k];

    // software pipeline: emit row for t=1 prefetched (T >= 2 always)
    float emit_next = emit[((size_t)BB + b) * NN + k];

    for (int t = 1; t < len; ++t) {
        const float emit_t = emit_next;
        if (t + 1 < TT)   // wave-uniform; prefetch next row (harmless if past len)
            emit_next = emit[((size_t)(t + 1) * BB + b) * NN + k];

        const float a0 = __uint_as_float(
            __builtin_amdgcn_readfirstlane(__float_as_uint(alpha)));
        const float p = __expf(alpha - a0);   // in [~5e-4, ~3e3], fp32-safe

        // single wave per block: DS ops are in-order per wave and the compiler
        // preserves write->read order on may-aliasing LDS accesses — no barrier.
        pbuf[k] = p;

        const float4* p4 = (const float4*)pbuf;
        float a0acc = 0.f, a1acc = 0.f, a2acc = 0.f, a3acc = 0.f;
        #pragma unroll
        for (int jj = 0; jj < NN / 4; ++jj) {
            const float4 pv = p4[jj];   // same-address broadcast (conflict-free)
            a0acc = fmaf(pv.x, E[4 * jj + 0], a0acc);
            a1acc = fmaf(pv.y, E[4 * jj + 1], a1acc);
            a2acc = fmaf(pv.z, E[4 * jj + 2], a2acc);
            a3acc = fmaf(pv.w, E[4 * jj + 3], a3acc);
        }
        const float acc = (a0acc + a1acc) + (a2acc + a3acc);

        alpha = a0 + __logf(acc) + emit_t;
    }

    // logZ_b = logsumexp_k(alpha + etrans)  — exact max here (once)
    const float la = alpha + etrans[k];
    const float m2 = wave_max(la);
    const float s2 = wave_sum(__expf(la - m2));
    if (k == 0) atomicAdd(out, m2 + __logf(s2));
}

// Gold score: sum over masked (t,b) of emit[t,b,tgt] (+ trans[tgt_prev,tgt] for t>0,
// + strans[tgt] for t==0, + etrans[tgt] at the last masked step). Subtracted from out.
__global__ __launch_bounds__(256) void crf_gold_kernel(
    const float* __restrict__ emit,
    const float* __restrict__ trans,
    const float* __restrict__ strans,
    const float* __restrict__ etrans,
    const int*   __restrict__ target,
    const void*  __restrict__ maskp,
    float* __restrict__ out)
{
    const int*           mi32 = (const int*)maskp;
    const unsigned char* mi8  = (const unsigned char*)maskp;
    const bool bytemode = (mi32[0] == 0x01010101);

    const int stride = gridDim.x * blockDim.x;
    float acc = 0.f;
    for (int i = blockIdx.x * blockDim.x + threadIdx.x; i < TT * BB; i += stride) {
        const int t = i >> 9;        // i / 512
        const bool mk = bytemode ? (mi8[i] != 0) : (mi32[i] != 0);
        if (mk) {
            const int tgt = target[i];
            float v = emit[(size_t)i * NN + tgt];
            if (t > 0)
                v += trans[target[i - BB] * NN + tgt];
            else
                v += strans[tgt];
            const bool is_end = (t == TT - 1) ||
                (bytemode ? (mi8[i + BB] == 0) : (mi32[i + BB] == 0));
            if (is_end) v += etrans[tgt];
            acc += v;
        }
    }

    // block reduction: wave shfl-reduce, then LDS across the 4 waves
    acc = wave_sum(acc);
    __shared__ float wsum[4];
    const int wid = threadIdx.x >> 6;
    if ((threadIdx.x & 63) == 0) wsum[wid] = acc;
    __syncthreads();
    if (threadIdx.x == 0) {
        const float s = (wsum[0] + wsum[1]) + (wsum[2] + wsum[3]);
        atomicAdd(out, -s);
    }
}

extern "C" void kernel_launch(void* const* d_in, const int* in_sizes, int n_in,
                              void* d_out, int out_size, void* d_ws, size_t ws_size,
                              hipStream_t stream) {
    const float* emit   = (const float*)d_in[0];
    const float* trans  = (const float*)d_in[1];
    const float* strans = (const float*)d_in[2];
    const float* etrans = (const float*)d_in[3];
    const int*   target = (const int*)d_in[4];
    const void*  mask   = d_in[5];
    float* out = (float*)d_out;

    hipLaunchKernelGGL(zero_kernel, dim3(1), dim3(64), 0, stream, out);
    hipLaunchKernelGGL(crf_fwd_kernel, dim3(BB), dim3(64), 0, stream,
                       emit, trans, strans, etrans, mask, out);
    hipLaunchKernelGGL(crf_gold_kernel, dim3(256), dim3(256), 0, stream,
                       emit, trans, strans, etrans, target, mask, out);
}

// Round 3
// 261.242 us; speedup vs baseline: 2.1281x; 1.2544x over previous
//
#include <hip/hip_runtime.h>

#define TT 512
#define BB 512
#define NN 64

__device__ __forceinline__ float wave_max(float v) {
    #pragma unroll
    for (int off = 32; off > 0; off >>= 1)
        v = fmaxf(v, __shfl_xor(v, off, 64));
    return v;
}

__device__ __forceinline__ float wave_sum(float v) {
    #pragma unroll
    for (int off = 32; off > 0; off >>= 1)
        v += __shfl_xor(v, off, 64);
    return v;
}

__device__ __forceinline__ int wave_sum_i(int v) {
    #pragma unroll
    for (int off = 32; off > 0; off >>= 1)
        v += __shfl_xor(v, off, 64);
    return v;
}

__device__ __forceinline__ float bcast_lane(float v, int lane) {
    return __uint_as_float(__builtin_amdgcn_readlane(__float_as_uint(v), lane));
}

// Zero the scalar output (harness poisons d_out with 0xAA before every launch).
__global__ void zero_kernel(float* __restrict__ out) {
    if (threadIdx.x == 0 && blockIdx.x == 0) out[0] = 0.0f;
}

// Forward algorithm: one wave (64 lanes) per batch element; lane = state k.
// alpha_new[k] = emit[t,b,k] + a0 + log( sum_j exp(alpha_j - a0) * exp(trans[j,k]) )
// Cross-lane exchange done with v_readlane->SGPR broadcast + SGPR-operand FMAs:
// no LDS round-trip on the critical path (the ds_write+lgkmcnt+ds_read chain
// was ~400+ cyc of the measured ~1100 cyc/step).
__global__ __launch_bounds__(64) void crf_fwd_kernel(
    const float* __restrict__ emit,
    const float* __restrict__ trans,
    const float* __restrict__ strans,
    const float* __restrict__ etrans,
    const void*  __restrict__ maskp,
    float* __restrict__ out)
{
    const int b = blockIdx.x;
    const int k = threadIdx.x;

    const int*           mi32 = (const int*)maskp;
    const unsigned char* mi8  = (const unsigned char*)maskp;
    // mask[0,:] is all-true (lengths >= 1): byte encoding -> word0 == 0x01010101.
    const bool bytemode = (mi32[0] == 0x01010101);

    // len[b] = sum_t mask[t,b]  (mask is monotone per column). One-time cost;
    // removes per-step mask loads from the T-loop critical path.
    int cnt = 0;
    #pragma unroll
    for (int i = 0; i < TT / 64; ++i) {
        const size_t tb = (size_t)(i * 64 + k) * BB + b;
        cnt += bytemode ? (mi8[tb] != 0) : (mi32[tb] != 0);
    }
    const int len = wave_sum_i(cnt);   // wave-uniform

    // E[j] = exp(trans[j][k]); |trans| ~< 0.6, E in [~0.6, ~1.7]. 64 VGPRs.
    float E[NN];
    #pragma unroll
    for (int j = 0; j < NN; ++j)
        E[j] = __expf(trans[j * NN + k]);

    // t = 0
    float alpha = emit[(size_t)b * NN + k] + strans[k];

    // software pipeline: emit row for t=1 prefetched (T >= 2 always)
    float emit_next = emit[((size_t)BB + b) * NN + k];

    for (int t = 1; t < len; ++t) {
        const float emit_t = emit_next;
        // branchless prefetch of next row (clamped; harmless overshoot past len)
        const int tn = (t + 1 < TT) ? (t + 1) : (TT - 1);
        emit_next = emit[((size_t)tn * BB + b) * NN + k];

        // cheap shift instead of exact max: spread of alpha is small, so
        // exp(alpha - a0) stays in [~1e-4, ~1e4] — fp32-safe.
        const float a0 = bcast_lane(alpha, 0);
        const float p = __expf(alpha - a0);

        // acc_k = sum_j p_j * E[j]  via SGPR broadcasts; 4 independent
        // accumulator chains; readlanes pipeline (no LDS latency).
        float s0 = 0.f, s1 = 0.f, s2 = 0.f, s3 = 0.f;
        #pragma unroll
        for (int j = 0; j < NN / 4; ++j) {
            const float p0 = bcast_lane(p, 4 * j + 0);
            const float p1 = bcast_lane(p, 4 * j + 1);
            const float p2 = bcast_lane(p, 4 * j + 2);
            const float p3 = bcast_lane(p, 4 * j + 3);
            s0 = fmaf(p0, E[4 * j + 0], s0);
            s1 = fmaf(p1, E[4 * j + 1], s1);
            s2 = fmaf(p2, E[4 * j + 2], s2);
            s3 = fmaf(p3, E[4 * j + 3], s3);
        }
        const float acc = (s0 + s1) + (s2 + s3);

        alpha = a0 + __logf(acc) + emit_t;
    }

    // logZ_b = logsumexp_k(alpha + etrans)  — exact max here (once)
    const float la = alpha + etrans[k];
    const float m2 = wave_max(la);
    const float sm = wave_sum(__expf(la - m2));
    if (k == 0) atomicAdd(out, m2 + __logf(sm));
}

// Gold score: sum over masked (t,b) of emit[t,b,tgt] (+ trans[tgt_prev,tgt] for t>0,
// + strans[tgt] for t==0, + etrans[tgt] at the last masked step). Subtracted from out.
// One element per thread (no grid-stride loop) to minimize the latency chain.
__global__ __launch_bounds__(256) void crf_gold_kernel(
    const float* __restrict__ emit,
    const float* __restrict__ trans,
    const float* __restrict__ strans,
    const float* __restrict__ etrans,
    const int*   __restrict__ target,
    const void*  __restrict__ maskp,
    float* __restrict__ out)
{
    const int*           mi32 = (const int*)maskp;
    const unsigned char* mi8  = (const unsigned char*)maskp;
    const bool bytemode = (mi32[0] == 0x01010101);

    const int i = blockIdx.x * blockDim.x + threadIdx.x;   // grid covers TT*BB
    float acc = 0.f;
    const int t = i >> 9;        // i / 512
    const bool mk = bytemode ? (mi8[i] != 0) : (mi32[i] != 0);
    if (mk) {
        const int tgt = target[i];
        float v = emit[(size_t)i * NN + tgt];
        if (t > 0)
            v += trans[target[i - BB] * NN + tgt];
        else
            v += strans[tgt];
        const bool is_end = (t == TT - 1) ||
            (bytemode ? (mi8[i + BB] == 0) : (mi32[i + BB] == 0));
        if (is_end) v += etrans[tgt];
        acc = v;
    }

    // block reduction: wave shfl-reduce, then LDS across the 4 waves
    acc = wave_sum(acc);
    __shared__ float wsum[4];
    const int wid = threadIdx.x >> 6;
    if ((threadIdx.x & 63) == 0) wsum[wid] = acc;
    __syncthreads();
    if (threadIdx.x == 0) {
        const float s = (wsum[0] + wsum[1]) + (wsum[2] + wsum[3]);
        atomicAdd(out, -s);
    }
}

extern "C" void kernel_launch(void* const* d_in, const int* in_sizes, int n_in,
                              void* d_out, int out_size, void* d_ws, size_t ws_size,
                              hipStream_t stream) {
    const float* emit   = (const float*)d_in[0];
    const float* trans  = (const float*)d_in[1];
    const float* strans = (const float*)d_in[2];
    const float* etrans = (const float*)d_in[3];
    const int*   target = (const int*)d_in[4];
    const void*  mask   = d_in[5];
    float* out = (float*)d_out;

    hipLaunchKernelGGL(zero_kernel, dim3(1), dim3(64), 0, stream, out);
    hipLaunchKernelGGL(crf_fwd_kernel, dim3(BB), dim3(64), 0, stream,
                       emit, trans, strans, etrans, mask, out);
    hipLaunchKernelGGL(crf_gold_kernel, dim3((TT * BB) / 256), dim3(256), 0, stream,
                       emit, trans, strans, etrans, target, mask, out);
}